// Round 1
// 445.859 us; speedup vs baseline: 1.0250x; 1.0250x over previous
//
#include <hip/hip_runtime.h>

// Problem constants (match reference file)
#define N_NODES 2000000
#define N_EDGES 32000000
#define N_OUT   400000          // N_NODES / 5
#define NBUCKET 256             // out-index buckets
#define BSZ     1568            // bucket width: 256*1568 = 401408 >= 400000; local fits 11 bits
#define CAP_BLK 32              // per-block per-bucket LDS staging capacity (u32)
#define CHUNK   16384           // edges per block, phase 1 (256 thr * 4 edges * 16 iters)
#define CAP_BKT 28672           // per-bucket payload capacity (lambda=25000, +23 sigma)
#define KSLICE  4               // phase-2 slices per bucket
#define CNT_STRIDE 16           // pad cursor counters: one per 64B cacheline

typedef int iv4 __attribute__((ext_vector_type(4)));
typedef unsigned uv4 __attribute__((ext_vector_type(4)));

// ---------------------------------------------------------------------------
// Phase 1: bin filtered edges into 256 buckets by out-index.
// payload u32 = (src << 11) | local, src < 2^21, local < 1568 < 2^11.
// LDS-staged per bucket; one global cursor atomic per (block,bucket) at flush.
// Rare staging overflow -> direct atomicAdd into the bucket's overflow row.
// CAP_BLK=32 + CHUNK=16384 keeps LDS at 34 KB -> 4 blocks/CU (vs 2 before):
// doubles the waves available to hide the ds_add_rtn latency chain.
// ---------------------------------------------------------------------------
__global__ __launch_bounds__(256, 4) void p1_bin(
    const int* __restrict__ src,
    const int* __restrict__ dst,
    const float* __restrict__ x,
    unsigned* __restrict__ cnt,        // [NBUCKET * CNT_STRIDE]
    float* __restrict__ overflow,      // [NBUCKET][BSZ]
    unsigned* __restrict__ payload)    // [NBUCKET][CAP_BKT]
{
    __shared__ unsigned s_cur[NBUCKET];
    __shared__ unsigned s_base[NBUCKET];
    __shared__ unsigned s_stage[NBUCKET][CAP_BLK];

    const int tid = threadIdx.x;
    if (tid < NBUCKET) s_cur[tid] = 0;
    __syncthreads();

    const long long blockStart = (long long)blockIdx.x * CHUNK;
    const int NIT = CHUNK / 1024;   // 16 iterations; 1024 edges per block-iter

    // software-pipelined streaming: prefetch next iter's int4 pair.
    // nontemporal: edges are read exactly once -> don't evict payload/x from L2.
    long long b0 = blockStart + (long long)tid * 4;
    bool valid0 = (b0 < N_EDGES);
    iv4 d4 = valid0 ? __builtin_nontemporal_load(reinterpret_cast<const iv4*>(dst + b0)) : (iv4)0;
    iv4 s4 = valid0 ? __builtin_nontemporal_load(reinterpret_cast<const iv4*>(src + b0)) : (iv4)0;

    for (int it = 0; it < NIT; ++it) {
        iv4 nd = (iv4)0, ns = (iv4)0;
        bool nvalid = false;
        if (it + 1 < NIT) {
            const long long bn = blockStart + (long long)(it + 1) * 1024 + tid * 4;
            nvalid = (bn < N_EDGES);
            if (nvalid) {
                nd = __builtin_nontemporal_load(reinterpret_cast<const iv4*>(dst + bn));
                ns = __builtin_nontemporal_load(reinterpret_cast<const iv4*>(src + bn));
            }
        }
        if (valid0) {
#pragma unroll
            for (int j = 0; j < 4; ++j) {
                const unsigned d = (unsigned)d4[j];
                if (d % 5u == 0u) {
                    const unsigned g = d / 5u;               // 0..399999
                    const unsigned b = g / (unsigned)BSZ;    // 0..255
                    const unsigned local = g - b * (unsigned)BSZ;
                    const unsigned p = ((unsigned)s4[j] << 11) | local;
                    const unsigned slot = atomicAdd(&s_cur[b], 1u);
                    if (slot < CAP_BLK) {
                        s_stage[b][slot] = p;
                    } else {
                        // rare (~5 sigma): direct device-scope add into overflow row
                        const float v = x[s4[j]];
                        atomicAdd(&overflow[(size_t)b * BSZ + local], v);
                    }
                }
            }
        }
        d4 = nd; s4 = ns; valid0 = nvalid;
    }
    __syncthreads();

    // reserve payload runs: 256 parallel cursor atomics (one 64B line each)
    if (tid < NBUCKET) {
        const unsigned c = min(s_cur[tid], (unsigned)CAP_BLK);
        s_cur[tid] = c;
        s_base[tid] = atomicAdd(&cnt[tid * CNT_STRIDE], c);
    }
    __syncthreads();

    // flush: each wave handles 64 buckets, two per iteration (32 lanes each)
    const int wave = tid >> 6, lane = tid & 63;
    const int half = lane >> 5, l = lane & 31;
    for (int i = 0; i < 32; ++i) {
        const int b = wave * 64 + i * 2 + half;
        const unsigned c = s_cur[b];
        const unsigned pos = s_base[b] + (unsigned)l;
        if ((unsigned)l < c && pos < (unsigned)CAP_BKT)
            payload[(size_t)b * CAP_BKT + pos] = s_stage[b][l];
    }
}

// ---------------------------------------------------------------------------
// Phase 2: per (bucket, slice): accumulate payload into a 1568-float LDS
// accumulator via ds_add_f32. 512-thread blocks -> 1024 blocks = 4 blocks/CU
// = 32 waves/CU (was 16): hides the payload-load -> x-gather latency chain.
// Per-thread contiguous dwordx4 payload loads (16B/lane, coalesced).
// ---------------------------------------------------------------------------
__global__ __launch_bounds__(512, 8) void p2_accum(
    const unsigned* __restrict__ cnt,
    const unsigned* __restrict__ payload,
    const float* __restrict__ x,
    float* __restrict__ partials)
{
    __shared__ float acc[BSZ];
    const int b = blockIdx.x >> 2;        // KSLICE = 4
    const int j = blockIdx.x & 3;
    const int tid = threadIdx.x;

    for (int i = tid; i < BSZ; i += 512) acc[i] = 0.0f;
    __syncthreads();

    unsigned n = cnt[b * CNT_STRIDE];
    if (n > CAP_BKT) n = CAP_BKT;         // safety clamp (never expected)
    // slice bounds rounded down to multiples of 4 so dwordx4 stays 16B-aligned
    unsigned beg = ((unsigned)(((unsigned long long)n * j) >> 2)) & ~3u;
    unsigned end = (j == KSLICE - 1) ? n
                 : ((unsigned)(((unsigned long long)n * (j + 1)) >> 2)) & ~3u;
    const unsigned* pb = payload + (size_t)b * CAP_BKT;

    unsigned base = beg + (unsigned)tid * 4u;
    for (; base + 3u < end; base += 512u * 4u) {
        const uv4 pv = *reinterpret_cast<const uv4*>(pb + base);
        float vv[4];
#pragma unroll
        for (int u = 0; u < 4; ++u) vv[u] = x[pv[u] >> 11];
#pragma unroll
        for (int u = 0; u < 4; ++u)
            __hip_atomic_fetch_add(&acc[pv[u] & 2047u], vv[u],
                                   __ATOMIC_RELAXED, __HIP_MEMORY_SCOPE_WORKGROUP);
    }
    if (base < end) {                     // per-thread ragged tail (< 4 entries)
        const unsigned stop = min(end, base + 4u);
        for (unsigned i = base; i < stop; ++i) {
            const unsigned p = pb[i];
            __hip_atomic_fetch_add(&acc[p & 2047u], x[p >> 11],
                                   __ATOMIC_RELAXED, __HIP_MEMORY_SCOPE_WORKGROUP);
        }
    }
    __syncthreads();

    float* row = partials + ((size_t)b * KSLICE + j) * BSZ;
    for (int i = tid; i < BSZ; i += 512) row[i] = acc[i];
}

// ---------------------------------------------------------------------------
// Phase 3: sum KSLICE partial rows + overflow row, folded affine + 2->4->1
// MLP, write out.
// ---------------------------------------------------------------------------
__global__ __launch_bounds__(256) void p3_out(
    const float* __restrict__ partials,
    const float* __restrict__ overflow,
    const float* __restrict__ w_conv,
    const float* __restrict__ b_conv,
    const float* __restrict__ w1,   // [2,4] row-major
    const float* __restrict__ b1,
    const float* __restrict__ w2,
    const float* __restrict__ b2,
    float* __restrict__ out)
{
    const int i = blockIdx.x * 256 + threadIdx.x;
    if (i >= N_OUT) return;
    const int b = i / BSZ;
    const int local = i - b * BSZ;
    const float* pr = partials + (size_t)b * KSLICE * BSZ + local;
    float s = overflow[(size_t)b * BSZ + local];
#pragma unroll
    for (int r = 0; r < KSLICE; ++r) s += pr[(size_t)r * BSZ];
    const float a = s * w_conv[0] + b_conv[0];
    float rr = b2[0];
#pragma unroll
    for (int jj = 0; jj < 4; ++jj) {
        float t = fmaf(a, w1[jj] + w1[4 + jj], b1[jj]);
        rr = fmaf(fmaxf(t, 0.0f), w2[jj], rr);
    }
    out[i] = rr;
}

// ---------------------------------------------------------------------------
// Fallback (ws too small): direct device-atomic scatter + epilogue.
// ---------------------------------------------------------------------------
__global__ __launch_bounds__(256, 4) void gcn_edge_scatter_dev(
    const int* __restrict__ src,
    const int* __restrict__ dst,
    const float* __restrict__ x,
    float* __restrict__ agg)
{
    const long long base = ((long long)blockIdx.x * blockDim.x + threadIdx.x) * 16;
    if (base >= N_EDGES) return;
    iv4 d4[4], s4[4];
#pragma unroll
    for (int c = 0; c < 4; ++c)
        d4[c] = *(reinterpret_cast<const iv4*>(dst + base) + c);
#pragma unroll
    for (int c = 0; c < 4; ++c)
        s4[c] = *(reinterpret_cast<const iv4*>(src + base) + c);
    int dd[16]; int idx[16]; bool pass[16];
#pragma unroll
    for (int c = 0; c < 4; ++c)
#pragma unroll
        for (int j = 0; j < 4; ++j) {
            const int d = d4[c][j];
            const bool p = (d % 5 == 0);
            dd[c * 4 + j] = d; pass[c * 4 + j] = p;
            idx[c * 4 + j] = p ? s4[c][j] : 0;
        }
    float v[16];
#pragma unroll
    for (int k = 0; k < 16; ++k) v[k] = x[idx[k]];
#pragma unroll
    for (int k = 0; k < 16; ++k)
        if (pass[k]) atomicAdd(&agg[dd[k] / 5], v[k]);
}

__global__ __launch_bounds__(256) void gcn_epilogue_fb(
    const float* __restrict__ agg,
    const float* __restrict__ w_conv, const float* __restrict__ b_conv,
    const float* __restrict__ w1, const float* __restrict__ b1,
    const float* __restrict__ w2, const float* __restrict__ b2,
    float* __restrict__ out)
{
    const int i = blockIdx.x * 256 + threadIdx.x;
    if (i >= N_OUT) return;
    const float a = agg[i] * w_conv[0] + b_conv[0];
    float r = b2[0];
#pragma unroll
    for (int j = 0; j < 4; ++j) {
        float t = fmaf(a, w1[j] + w1[4 + j], b1[j]);
        r = fmaf(fmaxf(t, 0.0f), w2[j], r);
    }
    out[i] = r;
}

extern "C" void kernel_launch(void* const* d_in, const int* in_sizes, int n_in,
                              void* d_out, int out_size, void* d_ws, size_t ws_size,
                              hipStream_t stream) {
    const float* x      = (const float*)d_in[0];
    const int*   ei     = (const int*)  d_in[1];  // [2, N_EDGES]: src row then dst row
    const float* w_conv = (const float*)d_in[2];
    const float* b_conv = (const float*)d_in[3];
    const float* w1     = (const float*)d_in[4];
    const float* b1     = (const float*)d_in[5];
    const float* w2     = (const float*)d_in[6];
    const float* b2     = (const float*)d_in[7];
    float* out = (float*)d_out;

    // ws layout: [cnt 16KB][overflow 1.6MB][partials 6.4MB][payload 29.4MB]
    // Only cnt + overflow need zeroing (p2 fully overwrites partials rows).
    const size_t cnt_bytes = (size_t)NBUCKET * CNT_STRIDE * sizeof(unsigned); // 16384
    const size_t ovf_off   = cnt_bytes;
    const size_t ovf_bytes = (size_t)NBUCKET * BSZ * sizeof(float);           // 1605632
    const size_t part_off  = (ovf_off + ovf_bytes + 255) & ~(size_t)255;
    const size_t part_bytes= (size_t)NBUCKET * KSLICE * BSZ * sizeof(float);  // 6422528
    const size_t pay_off   = (part_off + part_bytes + 255) & ~(size_t)255;
    const size_t pay_bytes = (size_t)NBUCKET * CAP_BKT * sizeof(unsigned);    // 29360128
    const size_t need      = pay_off + pay_bytes;

    if (ws_size >= need) {
        unsigned* cnt      = (unsigned*)d_ws;
        float*    overflow = (float*)((char*)d_ws + ovf_off);
        float*    partials = (float*)((char*)d_ws + part_off);
        unsigned* payload  = (unsigned*)((char*)d_ws + pay_off);

        (void)hipMemsetAsync(d_ws, 0, ovf_off + ovf_bytes, stream); // cnt + overflow

        const int grid_p1 = (int)((N_EDGES + CHUNK - 1) / CHUNK);   // 1954
        p1_bin<<<grid_p1, 256, 0, stream>>>(ei, ei + N_EDGES, x, cnt, overflow, payload);
        p2_accum<<<NBUCKET * KSLICE, 512, 0, stream>>>(cnt, payload, x, partials);
        p3_out<<<(N_OUT + 255) / 256, 256, 0, stream>>>(
            partials, overflow, w_conv, b_conv, w1, b1, w2, b2, out);
    } else {
        float* agg = (float*)d_ws;
        (void)hipMemsetAsync(agg, 0, (size_t)N_OUT * sizeof(float), stream);
        gcn_edge_scatter_dev<<<(N_EDGES / 16 + 255) / 256, 256, 0, stream>>>(
            ei, ei + N_EDGES, x, agg);
        gcn_epilogue_fb<<<(N_OUT + 255) / 256, 256, 0, stream>>>(
            agg, w_conv, b_conv, w1, b1, w2, b2, out);
    }
}